// Round 8
// baseline (871.660 us; speedup 1.0000x reference)
//
#include <hip/hip_runtime.h>

#define TT 1024   // timesteps
// batch = 512 sequences; 256 blocks x 2 sequences; 3 waves/block = 1 per layer.
// R8 theory: barrier-locked waves all stall on the same LDS/shuffle latency at
// the same moment -> TLP hides nothing (VALUBusy ~41% across R5-R7). Fix by
// IN-WAVE ILP: each wave time-multiplexes TWO independent sequences; seq1's
// dot issue hides seq0's LDS/shuffle latency. Weights fp32 in registers
// (shared by both seqs), k-split 16/lane across wave halves, asm-pinned.

typedef float v2f __attribute__((ext_vector_type(2)));

__device__ __forceinline__ v2f pk_mul(v2f a, v2f b) {
    v2f d; asm("v_pk_mul_f32 %0, %1, %2" : "=v"(d) : "v"(a), "v"(b)); return d;
}
__device__ __forceinline__ v2f pk_fma(v2f a, v2f b, v2f c) {
    v2f d; asm("v_pk_fma_f32 %0, %1, %2, %3" : "=v"(d) : "v"(a), "v"(b), "v"(c)); return d;
}
__device__ __forceinline__ v2f pk_add(v2f a, v2f b) {
    v2f d; asm("v_pk_add_f32 %0, %1, %2" : "=v"(d) : "v"(a), "v"(b)); return d;
}

__device__ __forceinline__ float fast_sigmoid(float x) {
    float e = __builtin_amdgcn_exp2f(x * -1.4426950408889634f);
    return __builtin_amdgcn_rcpf(1.0f + e);
}
__device__ __forceinline__ float fast_tanh(float x) {
    float e = __builtin_amdgcn_exp2f(x * -2.8853900817779268f);
    return fmaf(2.0f, __builtin_amdgcn_rcpf(1.0f + e), -1.0f);
}

// 3 gate dot products over a 16-k slice held as 8 packed f32 pairs.
__device__ __forceinline__ void dot3(const v2f (&w)[3][8], const v2f (&v)[8], float (&d)[3]) {
#pragma unroll
    for (int g = 0; g < 3; ++g) {
        v2f a = pk_mul(w[g][0], v[0]);
        v2f b = pk_mul(w[g][1], v[1]);
        a = pk_fma(w[g][2], v[2], a);
        b = pk_fma(w[g][3], v[3], b);
        a = pk_fma(w[g][4], v[4], a);
        b = pk_fma(w[g][5], v[5], b);
        a = pk_fma(w[g][6], v[6], a);
        b = pk_fma(w[g][7], v[7], b);
        a = pk_add(a, b);
        d[g] = a.x + a.y;
    }
}

// 16 consecutive floats -> 8 packed pairs
__device__ __forceinline__ void load8(const float* p, v2f (&v)[8]) {
    const float4 f0 = ((const float4*)p)[0];
    const float4 f1 = ((const float4*)p)[1];
    const float4 f2 = ((const float4*)p)[2];
    const float4 f3 = ((const float4*)p)[3];
    v[0] = v2f{f0.x, f0.y}; v[1] = v2f{f0.z, f0.w};
    v[2] = v2f{f1.x, f1.y}; v[3] = v2f{f1.z, f1.w};
    v[4] = v2f{f2.x, f2.y}; v[5] = v2f{f2.z, f2.w};
    v[6] = v2f{f3.x, f3.y}; v[7] = v2f{f3.z, f3.w};
}

// lgkm-only block barrier: LDS writes visible, global stores NOT drained.
__device__ __forceinline__ void sync_lgkm() {
    __builtin_amdgcn_sched_barrier(0);
    asm volatile("s_waitcnt lgkmcnt(0)" ::: "memory");
    __builtin_amdgcn_s_barrier();
    __builtin_amdgcn_sched_barrier(0);
}

// ybuf flat index: [layer][parity][seq][32]
#define YB(L, p, s) ((((L) * 2 + (p)) * 2 + (s)) * 32)

__global__ __launch_bounds__(192, 2) void gru3_fused(
    const float* __restrict__ x,
    const float* __restrict__ Wih1, const float* __restrict__ Whh1,
    const float* __restrict__ bih1, const float* __restrict__ bhh1,
    const float* __restrict__ Wih2, const float* __restrict__ Whh2,
    const float* __restrict__ bih2, const float* __restrict__ bhh2,
    const float* __restrict__ Wih3, const float* __restrict__ Whh3,
    const float* __restrict__ bih3, const float* __restrict__ bhh3,
    float* __restrict__ out)
{
    __shared__ float ybuf[3 * 2 * 2 * 32];   // 384 floats
    __shared__ float xs[2 * TT];             // 2 staged x rows (seqs are adjacent)

    const int tid  = threadIdx.x;
    const int wid  = __builtin_amdgcn_readfirstlane(tid >> 6);  // scalar layer id
    const int lane = tid & 63;
    const int h    = lane & 31;       // hidden unit
    const int kh   = lane >> 5;       // k-half (and seq index for publish/output)
    const int k0   = kh * 16;
    const int bb   = (int)blockIdx.x; // block = 2 sequences: 2*bb, 2*bb+1

    // ---- one-time staging ----
    if (tid < 192) { ybuf[tid] = 0.0f; ybuf[192 + tid] = 0.0f; }
    {
        const float4* xr4 = (const float4*)(x + 2 * bb * TT);   // 2 contiguous rows
        for (int j = tid; j < 2 * TT / 4; j += 192) ((float4*)xs)[j] = xr4[j];
    }

    // ---- per-lane register weights (packed pairs), k-slice k0..k0+15 ----
    const float* WhhP = (wid == 0) ? Whh1 : (wid == 1) ? Whh2 : Whh3;
    const float* WihP = (wid == 0) ? Whh1 : (wid == 1) ? Wih2 : Wih3;  // dummy for wave0
    v2f whh[3][8], wih[3][8];
#pragma unroll
    for (int g = 0; g < 3; ++g) {
        load8(WhhP + (g * 32 + h) * 32 + k0, whh[g]);
        load8(WihP + (g * 32 + h) * 32 + k0, wih[g]);
    }
    // PIN: force true register residency of the weight set.
#pragma unroll
    for (int g = 0; g < 3; ++g)
#pragma unroll
        for (int j = 0; j < 8; ++j) {
            asm volatile("" : "+v"(whh[g][j]));
            asm volatile("" : "+v"(wih[g][j]));
        }

    const float* bihp = (wid == 0) ? bih1 : (wid == 1) ? bih2 : bih3;
    const float* bhhp = (wid == 0) ? bhh1 : (wid == 1) ? bhh2 : bhh3;
    const float brz_r = bihp[h]      + bhhp[h];
    const float brz_z = bihp[32 + h] + bhhp[32 + h];
    const float b_in  = bihp[64 + h];
    const float b_hn  = bhhp[64 + h];
    float wi_r = 0.f, wi_z = 0.f, wi_n = 0.f;
    if (wid == 0) { wi_r = Wih1[h]; wi_z = Wih1[32 + h]; wi_n = Wih1[64 + h]; }

    __syncthreads();   // full barrier once after staging

    float hp0 = 0.0f, hp1 = 0.0f;   // running h for the 2 sequences
    // pipelined: at iteration i, wave L computes timestep t = i - L (both seqs)
    for (int i = 0; i < TT + 2; ++i) {
        const int t = i - wid;           // scalar
        if (t >= 0 && t < TT) {          // scalar branch
            const int p = t & 1;

            float r0, z0, n0, r1, z1, n1;
            if (wid != 0) {
                // load all 4 h-vectors first: maximal in-flight ILP
                v2f vi0[8], vi1[8], vo0[8], vo1[8];
                load8(ybuf + YB(wid - 1, p, 0) + k0, vi0);
                load8(ybuf + YB(wid - 1, p, 1) + k0, vi1);
                load8(ybuf + YB(wid, p ^ 1, 0) + k0, vo0);
                load8(ybuf + YB(wid, p ^ 1, 1) + k0, vo1);

                float di0[3], dh0[3], di1[3], dh1[3];
                dot3(wih, vi0, di0);
                dot3(wih, vi1, di1);   // independent chain: hides vo loads
                dot3(whh, vo0, dh0);
                dot3(whh, vo1, dh1);

                float cr0 = dh0[0] + di0[0]; cr0 += __shfl_xor(cr0, 32);
                float cz0 = dh0[1] + di0[1]; cz0 += __shfl_xor(cz0, 32);
                float ci0 = di0[2];          ci0 += __shfl_xor(ci0, 32);
                float ch0 = dh0[2];          ch0 += __shfl_xor(ch0, 32);
                float cr1 = dh1[0] + di1[0]; cr1 += __shfl_xor(cr1, 32);
                float cz1 = dh1[1] + di1[1]; cz1 += __shfl_xor(cz1, 32);
                float ci1 = di1[2];          ci1 += __shfl_xor(ci1, 32);
                float ch1 = dh1[2];          ch1 += __shfl_xor(ch1, 32);

                r0 = fast_sigmoid(cr0 + brz_r);
                z0 = fast_sigmoid(cz0 + brz_z);
                n0 = fast_tanh(ci0 + b_in + r0 * (ch0 + b_hn));
                r1 = fast_sigmoid(cr1 + brz_r);
                z1 = fast_sigmoid(cz1 + brz_z);
                n1 = fast_tanh(ci1 + b_in + r1 * (ch1 + b_hn));
            } else {
                const float xv0 = xs[t];
                const float xv1 = xs[TT + t];
                v2f vo0[8], vo1[8];
                load8(ybuf + YB(0, p ^ 1, 0) + k0, vo0);
                load8(ybuf + YB(0, p ^ 1, 1) + k0, vo1);
                float dh0[3], dh1[3];
                dot3(whh, vo0, dh0);
                dot3(whh, vo1, dh1);
                float sr0 = dh0[0]; sr0 += __shfl_xor(sr0, 32);
                float sz0 = dh0[1]; sz0 += __shfl_xor(sz0, 32);
                float sn0 = dh0[2]; sn0 += __shfl_xor(sn0, 32);
                float sr1 = dh1[0]; sr1 += __shfl_xor(sr1, 32);
                float sz1 = dh1[1]; sz1 += __shfl_xor(sz1, 32);
                float sn1 = dh1[2]; sn1 += __shfl_xor(sn1, 32);
                r0 = fast_sigmoid(fmaf(xv0, wi_r, sr0 + brz_r));
                z0 = fast_sigmoid(fmaf(xv0, wi_z, sz0 + brz_z));
                n0 = fast_tanh(fmaf(xv0, wi_n, b_in) + r0 * (sn0 + b_hn));
                r1 = fast_sigmoid(fmaf(xv1, wi_r, sr1 + brz_r));
                z1 = fast_sigmoid(fmaf(xv1, wi_z, sz1 + brz_z));
                n1 = fast_tanh(fmaf(xv1, wi_n, b_in) + r1 * (sn1 + b_hn));
            }
            const float hn0 = fmaf(z0, hp0 - n0, n0);
            const float hn1 = fmaf(z1, hp1 - n1, n1);
            hp0 = hn0; hp1 = hn1;

            // publish both seqs with one wave write: half kh writes seq kh
            const float hsel = kh ? hn1 : hn0;
            ybuf[YB(wid, p, kh) + h] = hsel;                        // 64 distinct addrs
            if (wid == 2)
                out[t * 16384 + (2 * bb + kh) * 32 + h] = hsel;     // [T,B,H] flat, 64 lanes
        }
        sync_lgkm();   // LDS-visibility barrier; global stores keep flying
    }
}

extern "C" void kernel_launch(void* const* d_in, const int* in_sizes, int n_in,
                              void* d_out, int out_size, void* d_ws, size_t ws_size,
                              hipStream_t stream) {
    const float* x    = (const float*)d_in[0];
    const float* Wih1 = (const float*)d_in[1];
    const float* Whh1 = (const float*)d_in[2];
    const float* bih1 = (const float*)d_in[3];
    const float* bhh1 = (const float*)d_in[4];
    const float* Wih2 = (const float*)d_in[5];
    const float* Whh2 = (const float*)d_in[6];
    const float* bih2 = (const float*)d_in[7];
    const float* bhh2 = (const float*)d_in[8];
    const float* Wih3 = (const float*)d_in[9];
    const float* Whh3 = (const float*)d_in[10];
    const float* bih3 = (const float*)d_in[11];
    const float* bhh3 = (const float*)d_in[12];

    gru3_fused<<<dim3(256), dim3(192), 0, stream>>>(
        x, Wih1, Whh1, bih1, bhh1,
        Wih2, Whh2, bih2, bhh2,
        Wih3, Whh3, bih3, bhh3,
        (float*)d_out);
}